// Round 15
// baseline (311.881 us; speedup 1.0000x reference)
//
#include <hip/hip_runtime.h>
#include <math.h>

#define NORI 20
#define NPTS 160
#define CDIM 128
#define TWO_PI_OVER_O (6.28318530717958647692f / 20.0f)
#define SW 132           // fp32 LDS row stride (s_bw1)
#define SAS 136          // s_act row stride in ushorts (f16), 272 B
#define SCL 256.0f       // activation storage scale (exact pow2)
#define ISCL 0.00390625f // 1/256

typedef __attribute__((ext_vector_type(8))) _Float16 half8v;
typedef __attribute__((ext_vector_type(4))) float float4v;

__device__ __forceinline__ float vexp2(float x) {
    float r;
    asm("v_exp_f32 %0, %1" : "=v"(r) : "v"(x));   // D = 2^S0, 1 HW instr
    return r;
}
__device__ __forceinline__ float vsqrt(float x) {
    float r;
    asm("v_sqrt_f32 %0, %1" : "=v"(r) : "v"(x));  // 1 HW instr, no libm fixup
    return r;
}

// Fast exact-GELU: A&S 7.1.26 erf (|err|<1.5e-7), exp via raw v_exp_f32
// (r14 PMC arithmetic: ~5000 VALU instr/thread vs ~2000 source-level —
// suspect __expf/sqrtf lowering to ocml routines; this pins the HW path).
__device__ __forceinline__ float gelu_exact(float x) {
    float t  = 0.70710678118654752440f * x;
    float at = fabsf(t);
    float tau = __builtin_amdgcn_rcpf(fmaf(0.3275911f, at, 1.0f));
    float p = fmaf(1.061405429f, tau, -1.453152027f);
    p = fmaf(p, tau, 1.421413741f);
    p = fmaf(p, tau, -0.284496736f);
    p = fmaf(p, tau, 0.254829592f);
    p = p * tau;
    float e = vexp2(t * t * -1.44269504088896340736f);   // exp(-t^2)
    float erf_abs = fmaf(-p, e, 1.0f);
    float hx = 0.5f * x;
    return fmaf(fabsf(hx), erf_abs, hx);
}
__device__ __forceinline__ float4 ld4(const float* p) { return *(const float4*)p; }
__device__ __forceinline__ unsigned short f16b(float f) {
    _Float16 h = (_Float16)f;                 // RNE convert
    return __builtin_bit_cast(unsigned short, h);
}
__device__ __forceinline__ float f16tof(unsigned short u) {
    return (float)__builtin_bit_cast(_Float16, u);
}
__device__ __forceinline__ unsigned int pkrtz(float a, float b) {
    auto h = __builtin_amdgcn_cvt_pkrtz(a, b);   // __fp16 ext_vector(2), 1 instr
    return __builtin_bit_cast(unsigned int, h);
}

#define FMA4(d, s, v) { d.x += (s)*(v).x; d.y += (s)*(v).y; d.z += (s)*(v).z; d.w += (s)*(v).w; }
#define GELU4(d) { d.x = gelu_exact(d.x); d.y = gelu_exact(d.y); \
                   d.z = gelu_exact(d.z); d.w = gelu_exact(d.w); }

// ---------------------------------------------------------------------------
// fk[l,p,o,c]  (stored f16)
// ---------------------------------------------------------------------------
__global__ __launch_bounds__(128) void fk_kernel(
    const float* __restrict__ fw1, const float* __restrict__ fb1,
    const float* __restrict__ fw2, const float* __restrict__ fb2,
    const float* __restrict__ fiber_w, unsigned short* __restrict__ fk)
{
    __shared__ float s_u[CDIM];
    __shared__ float s_z[CDIM];
    int bid = blockIdx.x;
    int l = bid / 400;
    int rem = bid % 400;
    int p = rem / 20, o = rem % 20;
    int j = threadIdx.x;

    float t = cosf(TWO_PI_OVER_O * (float)(p - o));
    float f1 = t * t, f2 = f1 * t;

    float u = gelu_exact(t * fw1[j] + f1 * fw1[CDIM + j] + f2 * fw1[2 * CDIM + j] + fb1[j]);
    s_u[j] = u;
    __syncthreads();

    float z0 = 0.f, z1 = 0.f, z2 = 0.f, z3 = 0.f;
    for (int i = 0; i < CDIM; i += 4) {
        z0 += s_u[i    ] * fw2[(i    ) * CDIM + j];
        z1 += s_u[i + 1] * fw2[(i + 1) * CDIM + j];
        z2 += s_u[i + 2] * fw2[(i + 2) * CDIM + j];
        z3 += s_u[i + 3] * fw2[(i + 3) * CDIM + j];
    }
    float z = gelu_exact(((z0 + z1) + (z2 + z3)) + fb2[j]);
    s_z[j] = z;
    __syncthreads();

    const float* fw = fiber_w + l * CDIM * CDIM;
    float a0 = 0.f, a1 = 0.f, a2 = 0.f, a3 = 0.f;
    for (int i = 0; i < CDIM; i += 4) {
        a0 += s_z[i    ] * fw[(i    ) * CDIM + j];
        a1 += s_z[i + 1] * fw[(i + 1) * CDIM + j];
        a2 += s_z[i + 2] * fw[(i + 2) * CDIM + j];
        a3 += s_z[i + 3] * fw[(i + 3) * CDIM + j];
    }
    fk[bid * CDIM + j] = f16b((a0 + a1) + (a2 + a3));
}

// ---------------------------------------------------------------------------
// h0
// ---------------------------------------------------------------------------
__global__ __launch_bounds__(128) void h0_kernel(
    const float* __restrict__ x, const float* __restrict__ emb_w,
    float* __restrict__ h)
{
    int row = blockIdx.x;
    int j = threadIdx.x;
    const float* xr = x + row * 16;
    float acc = 0.f;
#pragma unroll
    for (int i = 0; i < 16; ++i) acc += xr[i] * emb_w[i * CDIM + j];
    h[row * CDIM + j] = acc;
}

// ---------------------------------------------------------------------------
// wt: f16 transposed weights wt[mat][c][k] = f16(w[k][c])
// ---------------------------------------------------------------------------
__global__ __launch_bounds__(128) void wt_kernel(
    const float* __restrict__ bw2, const float* __restrict__ kernel_w,
    unsigned short* __restrict__ wt)
{
    int b = blockIdx.x;            // mat*128 + c
    int mat = b >> 7, c = b & 127;
    const float* src = (mat == 0) ? bw2 : (kernel_w + (mat - 1) * CDIM * CDIM);
    int k = threadIdx.x;
    wt[(mat * CDIM + c) * CDIM + k] = f16b(src[k * CDIM + c]);
}

// ---------------------------------------------------------------------------
// x1 kernel — MFMA path, 512 threads (8 waves, 16 cols/wave).
// (512,4): VGPR cap 128, no spill (r12: (512,6) cap 40 -> 500MB spill).
// ---------------------------------------------------------------------------
#define FOR_BANDS(X) X(0) X(1) X(2) X(3) X(4) X(5) X(6) X(7) X(8) X(9)

#define DECL_ACC(B) float4v acc##B = {0.f,0.f,0.f,0.f};

#define LDB(PTR, KT) (*(const half8v*)((PTR) + col0 * CDIM + (KT) * 32 + lh8))

#define LOADB(P, PTR) \
    half8v P##0 = LDB(PTR, 0); \
    half8v P##1 = LDB(PTR, 1); \
    half8v P##2 = LDB(PTR, 2); \
    half8v P##3 = LDB(PTR, 3);

#define G_BAND(B, P) { \
    const unsigned short* ar_ = s_act + (B) * 16 * SAS + abase; \
    half8v a0_ = *(const half8v*)(ar_); \
    half8v a1_ = *(const half8v*)(ar_ + 32); \
    half8v a2_ = *(const half8v*)(ar_ + 64); \
    half8v a3_ = *(const half8v*)(ar_ + 96); \
    acc##B = __builtin_amdgcn_mfma_f32_16x16x32_f16(a0_, P##0, acc##B, 0, 0, 0); \
    acc##B = __builtin_amdgcn_mfma_f32_16x16x32_f16(a1_, P##1, acc##B, 0, 0, 0); \
    acc##B = __builtin_amdgcn_mfma_f32_16x16x32_f16(a2_, P##2, acc##B, 0, 0, 0); \
    acc##B = __builtin_amdgcn_mfma_f32_16x16x32_f16(a3_, P##3, acc##B, 0, 0, 0); }

#define G1(B) G_BAND(B, bwf)
#define G2(B) G_BAND(B, kwf)

// z = gelu(256*acc + bb2), store z/256 as f16
#define ZW_BAND(B) { \
    int rb_ = (B) * 16 + lh4; \
    s_act[(rb_ + 0) * SAS + col0] = f16b(gelu_exact(fmaf(SCL, acc##B.x, zb0)) * ISCL); \
    s_act[(rb_ + 1) * SAS + col0] = f16b(gelu_exact(fmaf(SCL, acc##B.y, zb0)) * ISCL); \
    s_act[(rb_ + 2) * SAS + col0] = f16b(gelu_exact(fmaf(SCL, acc##B.z, zb0)) * ISCL); \
    s_act[(rb_ + 3) * SAS + col0] = f16b(gelu_exact(fmaf(SCL, acc##B.w, zb0)) * ISCL); \
    acc##B = vzero; }

#define H_BAND(B) { \
    int nb_ = (B) * 16 + lh4; \
    xacc0 += acc##B.x * hb0[(nb_ + 0) * 2560]; \
    xacc0 += acc##B.y * hb0[(nb_ + 1) * 2560]; \
    xacc0 += acc##B.z * hb0[(nb_ + 2) * 2560]; \
    xacc0 += acc##B.w * hb0[(nb_ + 3) * 2560]; }

__global__ __launch_bounds__(512, 4) void x1_kernel(
    const float* __restrict__ pos, const float* __restrict__ h,
    const float* __restrict__ bw1, const float* __restrict__ bb1,
    const float* __restrict__ bb2,
    const unsigned short* __restrict__ wtb,   // bw2^T f16 [c][k]
    const unsigned short* __restrict__ wtk,   // kernel_w[l]^T f16 [c][k]
    float* __restrict__ x1)
{
    __shared__ __align__(16) unsigned short s_act[160 * SAS];  // 43520 B
    __shared__ float s_bw1[9 * SW];                            // folded monomial weights
    __shared__ float s_bb1[CDIM];

    const int tid = threadIdx.x;
    const int rg = tid & 31;        // u-phase: 32 row groups
    const int cgv = tid >> 5;       // 16 col groups of 8
    const int c0u = cgv << 3;

    // fold 14 poly rows -> 9 monomials: {3,4}->ab, {7,8,10}->a2b, {9,11,12}->ab2
    if (tid < CDIM) {
        const int c = tid;
        s_bw1[0 * SW + c] = bw1[0 * CDIM + c];
        s_bw1[1 * SW + c] = bw1[1 * CDIM + c];
        s_bw1[2 * SW + c] = bw1[2 * CDIM + c];
        s_bw1[3 * SW + c] = bw1[3 * CDIM + c] + bw1[4 * CDIM + c];
        s_bw1[4 * SW + c] = bw1[5 * CDIM + c];
        s_bw1[5 * SW + c] = bw1[6 * CDIM + c];
        s_bw1[6 * SW + c] = bw1[7 * CDIM + c] + bw1[8 * CDIM + c] + bw1[10 * CDIM + c];
        s_bw1[7 * SW + c] = bw1[9 * CDIM + c] + bw1[11 * CDIM + c] + bw1[12 * CDIM + c];
        s_bw1[8 * SW + c] = bw1[13 * CDIM + c];
        s_bb1[c] = bb1[c];
    }

    const int m = blockIdx.x / NORI;
    const int o = blockIdx.x % NORI;
    const float th = TWO_PI_OVER_O * (float)o;
    const float ox = cosf(th), oy = sinf(th);
    const float pmx = pos[2 * m], pmy = pos[2 * m + 1];

    __syncthreads();

    // ---- u-phase (fp32 VALU): u = gelu(monomials @ bw1f + bb1) -> f16 LDS (u/256)
#pragma unroll
    for (int rr = 0; rr < 5; ++rr) {
        const int row = rr * 32 + rg;
        float rx = pos[2 * row] - pmx, ry = pos[2 * row + 1] - pmy;
        float ia = rx * ox + ry * oy;
        float ib = vsqrt(rx * rx + ry * ry) * fabsf(1.0f - ia);
        float q2a = ia * ia, q2m = ia * ib, q2b = ib * ib;
        float q3a = q2a * ia, q3m = q2a * ib, q3n = q2m * ib, q3b = q2b * ib;
        float4 ua = ld4(&s_bb1[c0u]);
        float4 ub = ld4(&s_bb1[c0u + 4]);
#define UF(I, S) { float4 wa_ = ld4(&s_bw1[(I) * SW + c0u]); \
                   float4 wb_ = ld4(&s_bw1[(I) * SW + c0u + 4]); \
                   FMA4(ua, S, wa_); FMA4(ub, S, wb_); }
        UF(0, ia) UF(1, ib) UF(2, q2a) UF(3, q2m) UF(4, q2b)
        UF(5, q3a) UF(6, q3m) UF(7, q3n) UF(8, q3b)
#undef UF
        GELU4(ua) GELU4(ub)
        uint4 up;
        up.x = pkrtz(ua.x * ISCL, ua.y * ISCL);
        up.y = pkrtz(ua.z * ISCL, ua.w * ISCL);
        up.z = pkrtz(ub.x * ISCL, ub.y * ISCL);
        up.w = pkrtz(ub.z * ISCL, ub.w * ISCL);
        *(uint4*)&s_act[row * SAS + c0u] = up;
    }

    // ---- MFMA setup: wave wv owns cols [wv*16, wv*16+16)
    const int lane = tid & 63;
    const int wv = tid >> 6;          // 0..7
    const int li = lane & 15;
    const int lh = lane >> 4;
    const int lh8 = lh << 3, lh4 = lh << 2;
    const int col0 = wv * 16 + li;
    const int abase = li * SAS + lh8;
    const float4v vzero = {0.f, 0.f, 0.f, 0.f};

    FOR_BANDS(DECL_ACC)
    LOADB(bwf, wtb)                    // B-frags for GEMM1, in flight over barrier
    __syncthreads();                   // u visible

    FOR_BANDS(G1)                      // acc = (u/256) @ bw2
    __syncthreads();                   // all A-reads of u done

    const float zb0 = bb2[col0];
    FOR_BANDS(ZW_BAND)                 // z = gelu(256*acc + bb2); store z/256
    LOADB(kwf, wtk)                    // B-frags for GEMM2
    __syncthreads();                   // z visible

    FOR_BANDS(G2)                      // acc = (z/256) @ kw = kern/256

    // ---- x1 partial: 256 * sum_n acc[n][c] * h[n,o,c]
    const float* hb0 = h + o * CDIM + col0;
    float xacc0 = 0.f;
    FOR_BANDS(H_BAND)

    xacc0 += __shfl_xor(xacc0, 16, 64);
    xacc0 += __shfl_xor(xacc0, 32, 64);

    if (lane < 16)
        x1[(m * NORI + o) * CDIM + col0] = xacc0 * SCL;
}

// ---------------------------------------------------------------------------
// fiber conv + LN + MLP + residual: 2 p-rows per block, grid = 160*10
// ---------------------------------------------------------------------------
__global__ __launch_bounds__(128) void mlp_kernel(
    const float* __restrict__ x1, const unsigned short* __restrict__ fk_l,
    const float* __restrict__ conv_b, const float* __restrict__ ln_g,
    const float* __restrict__ ln_b,
    const float* __restrict__ w1, const float* __restrict__ b1,
    const float* __restrict__ w2, const float* __restrict__ b2,
    float* __restrict__ h)
{
    __shared__ float s_xn[2][132];
    __shared__ float s_mid[2][520];
    __shared__ float s_s1[2][2], s_sq[2][2];

    const int c = threadIdx.x;
    const int m = blockIdx.x / 10, pg = blockIdx.x % 10;
    const int lane = c & 63, wid = c >> 6;

    float x1v[NORI];
#pragma unroll
    for (int o = 0; o < NORI; ++o) x1v[o] = x1[(m * NORI + o) * CDIM + c];

    float x2v[2];
#pragma unroll
    for (int rr = 0; rr < 2; ++rr) {
        int p = pg * 2 + rr;
        float x2 = 0.f;
#pragma unroll
        for (int o = 0; o < NORI; ++o) x2 += x1v[o] * f16tof(fk_l[(p * NORI + o) * CDIM + c]);
        x2 = x2 * (1.0f / 128.0f) + conv_b[c];
        x2v[rr] = x2;
        float s1 = x2, sq = x2 * x2;
        for (int off = 32; off; off >>= 1) {
            s1 += __shfl_down(s1, off, 64);
            sq += __shfl_down(sq, off, 64);
        }
        if (lane == 0) { s_s1[rr][wid] = s1; s_sq[rr][wid] = sq; }
    }
    __syncthreads();
#pragma unroll
    for (int rr = 0; rr < 2; ++rr) {
        float mu  = (s_s1[rr][0] + s_s1[rr][1]) * (1.0f / 128.0f);
        float var = (s_sq[rr][0] + s_sq[rr][1]) * (1.0f / 128.0f) - mu * mu;
        float xn = (x2v[rr] - mu) * rsqrtf(var + 1e-5f) * ln_g[c] + ln_b[c];
        s_xn[rr][c] = xn;
    }
    __syncthreads();

#pragma unroll
    for (int kq = 0; kq < 4; ++kq) {
        int k = kq * CDIM + c;
        float b = b1[k];
        float ac0 = b, ac1 = b;
        for (int i = 0; i < CDIM; ++i) {
            float w = w1[i * 512 + k];
            ac0 += s_xn[0][i] * w;
            ac1 += s_xn[1][i] * w;
        }
        s_mid[0][k] = gelu_exact(ac0);
        s_mid[1][k] = gelu_exact(ac1);
    }
    __syncthreads();

    float ao0 = 0.f, ao1 = 0.f;
    for (int k = 0; k < 512; ++k) {
        float w = w2[k * CDIM + c];
        ao0 += s_mid[0][k] * w;
        ao1 += s_mid[1][k] * w;
    }
    float bb = b2[c];
    h[(m * NORI + pg * 2 + 0) * CDIM + c] += ao0 + bb;
    h[(m * NORI + pg * 2 + 1) * CDIM + c] += ao1 + bb;
}

// ---------------------------------------------------------------------------
extern "C" void kernel_launch(void* const* d_in, const int* in_sizes, int n_in,
                              void* d_out, int out_size, void* d_ws, size_t ws_size,
                              hipStream_t stream)
{
    const float* x        = (const float*)d_in[0];
    const float* pos      = (const float*)d_in[1];
    const float* bw1      = (const float*)d_in[2];
    const float* bb1      = (const float*)d_in[3];
    const float* bw2      = (const float*)d_in[4];
    const float* bb2      = (const float*)d_in[5];
    const float* fw1      = (const float*)d_in[6];
    const float* fb1      = (const float*)d_in[7];
    const float* fw2      = (const float*)d_in[8];
    const float* fb2      = (const float*)d_in[9];
    const float* emb_w    = (const float*)d_in[10];
    const float* kernel_w = (const float*)d_in[11];
    const float* fiber_w  = (const float*)d_in[12];
    const float* conv_b   = (const float*)d_in[13];
    const float* ln_g     = (const float*)d_in[14];
    const float* ln_b     = (const float*)d_in[15];
    const float* mlp_w1   = (const float*)d_in[16];
    const float* mlp_b1   = (const float*)d_in[17];
    const float* mlp_w2   = (const float*)d_in[18];
    const float* mlp_b2   = (const float*)d_in[19];

    float* h = (float*)d_out;                       // [160,20,128]

    // ws layout (total 1,941,504 B, inside the r5-proven [0, 2,048,000 B)):
    unsigned short* wt = (unsigned short*)d_ws;     // [3][128][128] f16 = 98,304 B
    unsigned short* fk = wt + 3 * CDIM * CDIM;      // [2,20,20,128] f16 = 204,800 B
    float* x1 = (float*)(fk + 2 * NORI * NORI * CDIM);  // [160,20,128] f32 = 1,638,400 B

    wt_kernel<<<3 * CDIM, 128, 0, stream>>>(bw2, kernel_w, wt);
    fk_kernel<<<2 * NORI * NORI, 128, 0, stream>>>(fw1, fb1, fw2, fb2, fiber_w, fk);
    h0_kernel<<<NPTS * NORI, 128, 0, stream>>>(x, emb_w, h);

    for (int l = 0; l < 2; ++l) {
        x1_kernel<<<NPTS * NORI, 512, 0, stream>>>(
            pos, h, bw1, bb1, bb2, wt, wt + (1 + l) * CDIM * CDIM, x1);
        mlp_kernel<<<NPTS * NORI / 2, 128, 0, stream>>>(
            x1, fk + l * NORI * NORI * CDIM,
            conv_b + l * CDIM, ln_g + l * CDIM, ln_b + l * CDIM,
            mlp_w1 + l * CDIM * 4 * CDIM, mlp_b1 + l * 4 * CDIM,
            mlp_w2 + l * 4 * CDIM * CDIM, mlp_b2 + l * CDIM, h);
    }
}

// Round 16
// 288.641 us; speedup vs baseline: 1.0805x; 1.0805x over previous
//
#include <hip/hip_runtime.h>
#include <math.h>

#define NORI 20
#define NPTS 160
#define CDIM 128
#define TWO_PI_OVER_O (6.28318530717958647692f / 20.0f)
#define SW 132           // fp32 LDS row stride (s_bw1)
#define SAS 136          // s_act row stride in ushorts (f16), 272 B
#define SCL 256.0f       // activation storage scale (exact pow2)
#define ISCL 0.00390625f // 1/256

typedef __attribute__((ext_vector_type(8))) _Float16 half8v;
typedef __attribute__((ext_vector_type(4))) float float4v;

__device__ __forceinline__ float vexp2(float x) {
    float r;
    asm("v_exp_f32 %0, %1" : "=v"(r) : "v"(x));   // D = 2^S0, 1 HW instr
    return r;
}
__device__ __forceinline__ float vsqrt(float x) {
    float r;
    asm("v_sqrt_f32 %0, %1" : "=v"(r) : "v"(x));  // 1 HW instr
    return r;
}

// Fast exact-GELU: A&S 7.1.26 erf (|err|<1.5e-7), exp via raw v_exp_f32.
__device__ __forceinline__ float gelu_exact(float x) {
    float t  = 0.70710678118654752440f * x;
    float at = fabsf(t);
    float tau = __builtin_amdgcn_rcpf(fmaf(0.3275911f, at, 1.0f));
    float p = fmaf(1.061405429f, tau, -1.453152027f);
    p = fmaf(p, tau, 1.421413741f);
    p = fmaf(p, tau, -0.284496736f);
    p = fmaf(p, tau, 0.254829592f);
    p = p * tau;
    float e = vexp2(t * t * -1.44269504088896340736f);   // exp(-t^2)
    float erf_abs = fmaf(-p, e, 1.0f);
    float hx = 0.5f * x;
    return fmaf(fabsf(hx), erf_abs, hx);
}
__device__ __forceinline__ float4 ld4(const float* p) { return *(const float4*)p; }
__device__ __forceinline__ unsigned short f16b(float f) {
    _Float16 h = (_Float16)f;                 // RNE convert
    return __builtin_bit_cast(unsigned short, h);
}
__device__ __forceinline__ float f16tof(unsigned short u) {
    return (float)__builtin_bit_cast(_Float16, u);
}
__device__ __forceinline__ unsigned int pkrtz(float a, float b) {
    auto h = __builtin_amdgcn_cvt_pkrtz(a, b);   // __fp16 ext_vector(2), 1 instr
    return __builtin_bit_cast(unsigned int, h);
}

#define FMA4(d, s, v) { d.x += (s)*(v).x; d.y += (s)*(v).y; d.z += (s)*(v).z; d.w += (s)*(v).w; }
#define GELU4(d) { d.x = gelu_exact(d.x); d.y = gelu_exact(d.y); \
                   d.z = gelu_exact(d.z); d.w = gelu_exact(d.w); }

// ---------------------------------------------------------------------------
// fk[l,p,o,c]  (stored f16)
// ---------------------------------------------------------------------------
__global__ __launch_bounds__(128) void fk_kernel(
    const float* __restrict__ fw1, const float* __restrict__ fb1,
    const float* __restrict__ fw2, const float* __restrict__ fb2,
    const float* __restrict__ fiber_w, unsigned short* __restrict__ fk)
{
    __shared__ float s_u[CDIM];
    __shared__ float s_z[CDIM];
    int bid = blockIdx.x;
    int l = bid / 400;
    int rem = bid % 400;
    int p = rem / 20, o = rem % 20;
    int j = threadIdx.x;

    float t = cosf(TWO_PI_OVER_O * (float)(p - o));
    float f1 = t * t, f2 = f1 * t;

    float u = gelu_exact(t * fw1[j] + f1 * fw1[CDIM + j] + f2 * fw1[2 * CDIM + j] + fb1[j]);
    s_u[j] = u;
    __syncthreads();

    float z0 = 0.f, z1 = 0.f, z2 = 0.f, z3 = 0.f;
    for (int i = 0; i < CDIM; i += 4) {
        z0 += s_u[i    ] * fw2[(i    ) * CDIM + j];
        z1 += s_u[i + 1] * fw2[(i + 1) * CDIM + j];
        z2 += s_u[i + 2] * fw2[(i + 2) * CDIM + j];
        z3 += s_u[i + 3] * fw2[(i + 3) * CDIM + j];
    }
    float z = gelu_exact(((z0 + z1) + (z2 + z3)) + fb2[j]);
    s_z[j] = z;
    __syncthreads();

    const float* fw = fiber_w + l * CDIM * CDIM;
    float a0 = 0.f, a1 = 0.f, a2 = 0.f, a3 = 0.f;
    for (int i = 0; i < CDIM; i += 4) {
        a0 += s_z[i    ] * fw[(i    ) * CDIM + j];
        a1 += s_z[i + 1] * fw[(i + 1) * CDIM + j];
        a2 += s_z[i + 2] * fw[(i + 2) * CDIM + j];
        a3 += s_z[i + 3] * fw[(i + 3) * CDIM + j];
    }
    fk[bid * CDIM + j] = f16b((a0 + a1) + (a2 + a3));
}

// ---------------------------------------------------------------------------
// h0
// ---------------------------------------------------------------------------
__global__ __launch_bounds__(128) void h0_kernel(
    const float* __restrict__ x, const float* __restrict__ emb_w,
    float* __restrict__ h)
{
    int row = blockIdx.x;
    int j = threadIdx.x;
    const float* xr = x + row * 16;
    float acc = 0.f;
#pragma unroll
    for (int i = 0; i < 16; ++i) acc += xr[i] * emb_w[i * CDIM + j];
    h[row * CDIM + j] = acc;
}

// ---------------------------------------------------------------------------
// wt: f16 transposed weights wt[mat][c][k] = f16(w[k][c])
// ---------------------------------------------------------------------------
__global__ __launch_bounds__(128) void wt_kernel(
    const float* __restrict__ bw2, const float* __restrict__ kernel_w,
    unsigned short* __restrict__ wt)
{
    int b = blockIdx.x;            // mat*128 + c
    int mat = b >> 7, c = b & 127;
    const float* src = (mat == 0) ? bw2 : (kernel_w + (mat - 1) * CDIM * CDIM);
    int k = threadIdx.x;
    wt[(mat * CDIM + c) * CDIM + k] = f16b(src[k * CDIM + c]);
}

// ---------------------------------------------------------------------------
// x1 kernel — UNCHANGED from r15 (frozen control; 118 µs/dispatch)
// ---------------------------------------------------------------------------
#define FOR_BANDS(X) X(0) X(1) X(2) X(3) X(4) X(5) X(6) X(7) X(8) X(9)

#define DECL_ACC(B) float4v acc##B = {0.f,0.f,0.f,0.f};

#define LDB(PTR, KT) (*(const half8v*)((PTR) + col0 * CDIM + (KT) * 32 + lh8))

#define LOADB(P, PTR) \
    half8v P##0 = LDB(PTR, 0); \
    half8v P##1 = LDB(PTR, 1); \
    half8v P##2 = LDB(PTR, 2); \
    half8v P##3 = LDB(PTR, 3);

#define G_BAND(B, P) { \
    const unsigned short* ar_ = s_act + (B) * 16 * SAS + abase; \
    half8v a0_ = *(const half8v*)(ar_); \
    half8v a1_ = *(const half8v*)(ar_ + 32); \
    half8v a2_ = *(const half8v*)(ar_ + 64); \
    half8v a3_ = *(const half8v*)(ar_ + 96); \
    acc##B = __builtin_amdgcn_mfma_f32_16x16x32_f16(a0_, P##0, acc##B, 0, 0, 0); \
    acc##B = __builtin_amdgcn_mfma_f32_16x16x32_f16(a1_, P##1, acc##B, 0, 0, 0); \
    acc##B = __builtin_amdgcn_mfma_f32_16x16x32_f16(a2_, P##2, acc##B, 0, 0, 0); \
    acc##B = __builtin_amdgcn_mfma_f32_16x16x32_f16(a3_, P##3, acc##B, 0, 0, 0); }

#define G1(B) G_BAND(B, bwf)
#define G2(B) G_BAND(B, kwf)

#define ZW_BAND(B) { \
    int rb_ = (B) * 16 + lh4; \
    s_act[(rb_ + 0) * SAS + col0] = f16b(gelu_exact(fmaf(SCL, acc##B.x, zb0)) * ISCL); \
    s_act[(rb_ + 1) * SAS + col0] = f16b(gelu_exact(fmaf(SCL, acc##B.y, zb0)) * ISCL); \
    s_act[(rb_ + 2) * SAS + col0] = f16b(gelu_exact(fmaf(SCL, acc##B.z, zb0)) * ISCL); \
    s_act[(rb_ + 3) * SAS + col0] = f16b(gelu_exact(fmaf(SCL, acc##B.w, zb0)) * ISCL); \
    acc##B = vzero; }

#define H_BAND(B) { \
    int nb_ = (B) * 16 + lh4; \
    xacc0 += acc##B.x * hb0[(nb_ + 0) * 2560]; \
    xacc0 += acc##B.y * hb0[(nb_ + 1) * 2560]; \
    xacc0 += acc##B.z * hb0[(nb_ + 2) * 2560]; \
    xacc0 += acc##B.w * hb0[(nb_ + 3) * 2560]; }

__global__ __launch_bounds__(512, 4) void x1_kernel(
    const float* __restrict__ pos, const float* __restrict__ h,
    const float* __restrict__ bw1, const float* __restrict__ bb1,
    const float* __restrict__ bb2,
    const unsigned short* __restrict__ wtb,   // bw2^T f16 [c][k]
    const unsigned short* __restrict__ wtk,   // kernel_w[l]^T f16 [c][k]
    float* __restrict__ x1)
{
    __shared__ __align__(16) unsigned short s_act[160 * SAS];  // 43520 B
    __shared__ float s_bw1[9 * SW];
    __shared__ float s_bb1[CDIM];

    const int tid = threadIdx.x;
    const int rg = tid & 31;
    const int cgv = tid >> 5;
    const int c0u = cgv << 3;

    if (tid < CDIM) {
        const int c = tid;
        s_bw1[0 * SW + c] = bw1[0 * CDIM + c];
        s_bw1[1 * SW + c] = bw1[1 * CDIM + c];
        s_bw1[2 * SW + c] = bw1[2 * CDIM + c];
        s_bw1[3 * SW + c] = bw1[3 * CDIM + c] + bw1[4 * CDIM + c];
        s_bw1[4 * SW + c] = bw1[5 * CDIM + c];
        s_bw1[5 * SW + c] = bw1[6 * CDIM + c];
        s_bw1[6 * SW + c] = bw1[7 * CDIM + c] + bw1[8 * CDIM + c] + bw1[10 * CDIM + c];
        s_bw1[7 * SW + c] = bw1[9 * CDIM + c] + bw1[11 * CDIM + c] + bw1[12 * CDIM + c];
        s_bw1[8 * SW + c] = bw1[13 * CDIM + c];
        s_bb1[c] = bb1[c];
    }

    const int m = blockIdx.x / NORI;
    const int o = blockIdx.x % NORI;
    const float th = TWO_PI_OVER_O * (float)o;
    const float ox = cosf(th), oy = sinf(th);
    const float pmx = pos[2 * m], pmy = pos[2 * m + 1];

    __syncthreads();

#pragma unroll
    for (int rr = 0; rr < 5; ++rr) {
        const int row = rr * 32 + rg;
        float rx = pos[2 * row] - pmx, ry = pos[2 * row + 1] - pmy;
        float ia = rx * ox + ry * oy;
        float ib = vsqrt(rx * rx + ry * ry) * fabsf(1.0f - ia);
        float q2a = ia * ia, q2m = ia * ib, q2b = ib * ib;
        float q3a = q2a * ia, q3m = q2a * ib, q3n = q2m * ib, q3b = q2b * ib;
        float4 ua = ld4(&s_bb1[c0u]);
        float4 ub = ld4(&s_bb1[c0u + 4]);
#define UF(I, S) { float4 wa_ = ld4(&s_bw1[(I) * SW + c0u]); \
                   float4 wb_ = ld4(&s_bw1[(I) * SW + c0u + 4]); \
                   FMA4(ua, S, wa_); FMA4(ub, S, wb_); }
        UF(0, ia) UF(1, ib) UF(2, q2a) UF(3, q2m) UF(4, q2b)
        UF(5, q3a) UF(6, q3m) UF(7, q3n) UF(8, q3b)
#undef UF
        GELU4(ua) GELU4(ub)
        uint4 up;
        up.x = pkrtz(ua.x * ISCL, ua.y * ISCL);
        up.y = pkrtz(ua.z * ISCL, ua.w * ISCL);
        up.z = pkrtz(ub.x * ISCL, ub.y * ISCL);
        up.w = pkrtz(ub.z * ISCL, ub.w * ISCL);
        *(uint4*)&s_act[row * SAS + c0u] = up;
    }

    const int lane = tid & 63;
    const int wv = tid >> 6;
    const int li = lane & 15;
    const int lh = lane >> 4;
    const int lh8 = lh << 3, lh4 = lh << 2;
    const int col0 = wv * 16 + li;
    const int abase = li * SAS + lh8;
    const float4v vzero = {0.f, 0.f, 0.f, 0.f};

    FOR_BANDS(DECL_ACC)
    LOADB(bwf, wtb)
    __syncthreads();

    FOR_BANDS(G1)
    __syncthreads();

    const float zb0 = bb2[col0];
    FOR_BANDS(ZW_BAND)
    LOADB(kwf, wtk)
    __syncthreads();

    FOR_BANDS(G2)

    const float* hb0 = h + o * CDIM + col0;
    float xacc0 = 0.f;
    FOR_BANDS(H_BAND)

    xacc0 += __shfl_xor(xacc0, 16, 64);
    xacc0 += __shfl_xor(xacc0, 32, 64);

    if (lane < 16)
        x1[(m * NORI + o) * CDIM + col0] = xacc0 * SCL;
}

// ---------------------------------------------------------------------------
// fiber conv + LN + MLP + residual: block per (m, p-half), 10 rows, 256 thr.
// r15 analysis: previous 1600-block version streamed w1+w2 (524 KB) per
// block = 838 MB L2/dispatch ~ 24 us L2-bound. 10 rows/block cuts weight
// traffic 5x; xn/mid staged in LDS; math identical (fp32, same gelu/LN).
// ---------------------------------------------------------------------------
__global__ __launch_bounds__(256, 2) void mlp_kernel(
    const float* __restrict__ x1, const unsigned short* __restrict__ fk_l,
    const float* __restrict__ conv_b, const float* __restrict__ ln_g,
    const float* __restrict__ ln_b,
    const float* __restrict__ w1, const float* __restrict__ b1,
    const float* __restrict__ w2, const float* __restrict__ b2,
    float* __restrict__ h)
{
    __shared__ float s_xn[10][132];      // 5280 B
    __shared__ float s_mid[10][520];     // 20800 B
    __shared__ float s_s1[2][5][2], s_sq[2][5][2];

    const int tid = threadIdx.x;
    const int m = blockIdx.x >> 1, ph = blockIdx.x & 1;
    const int c = tid & 127;
    const int pg2 = tid >> 7;            // 0/1: owns local rows pg2+2j
    const int lane = tid & 63;
    const int wig = (tid >> 6) & 1;      // wave within 128-thread group

    // x1 column c for all 20 o (global; L2-resident; same values as before)
    float x1v[NORI];
#pragma unroll
    for (int o = 0; o < NORI; ++o) x1v[o] = x1[(m * NORI + o) * CDIM + c];

    const float cb = conv_b[c], lg = ln_g[c], lb = ln_b[c];

    // fiber conv: 5 rows per thread
    float x2v[5];
#pragma unroll
    for (int j = 0; j < 5; ++j) {
        const int p = ph * 10 + pg2 + 2 * j;
        float acc = 0.f;
#pragma unroll
        for (int o = 0; o < NORI; ++o)
            acc += x1v[o] * f16tof(fk_l[(p * NORI + o) * CDIM + c]);
        x2v[j] = acc * (1.0f / 128.0f) + cb;
    }

    // batched LN reductions (5 independent rows per group)
    float s1v[5], sqv[5];
#pragma unroll
    for (int j = 0; j < 5; ++j) { s1v[j] = x2v[j]; sqv[j] = x2v[j] * x2v[j]; }
    for (int off = 32; off; off >>= 1) {
#pragma unroll
        for (int j = 0; j < 5; ++j) {
            s1v[j] += __shfl_down(s1v[j], off, 64);
            sqv[j] += __shfl_down(sqv[j], off, 64);
        }
    }
    if (lane == 0) {
#pragma unroll
        for (int j = 0; j < 5; ++j) { s_s1[pg2][j][wig] = s1v[j]; s_sq[pg2][j][wig] = sqv[j]; }
    }
    __syncthreads();
#pragma unroll
    for (int j = 0; j < 5; ++j) {
        const int pl = pg2 + 2 * j;
        float mu  = (s_s1[pg2][j][0] + s_s1[pg2][j][1]) * (1.0f / 128.0f);
        float var = (s_sq[pg2][j][0] + s_sq[pg2][j][1]) * (1.0f / 128.0f) - mu * mu;
        s_xn[pl][c] = (x2v[j] - mu) * rsqrtf(var + 1e-5f) * lg + lb;
    }
    __syncthreads();

    // mlp1: thread owns k-cols {tid, tid+256}, all 10 rows
    {
        float a0[10], a1[10];
#pragma unroll
        for (int r = 0; r < 10; ++r) { a0[r] = 0.f; a1[r] = 0.f; }
        const int k0 = tid, k1 = tid + 256;
        for (int i4 = 0; i4 < 128; i4 += 4) {
            float w00 = w1[(i4 + 0) * 512 + k0], w01 = w1[(i4 + 1) * 512 + k0];
            float w02 = w1[(i4 + 2) * 512 + k0], w03 = w1[(i4 + 3) * 512 + k0];
            float w10 = w1[(i4 + 0) * 512 + k1], w11 = w1[(i4 + 1) * 512 + k1];
            float w12 = w1[(i4 + 2) * 512 + k1], w13 = w1[(i4 + 3) * 512 + k1];
#pragma unroll
            for (int r = 0; r < 10; ++r) {
                float4 xr = ld4(&s_xn[r][i4]);
                a0[r] = fmaf(xr.x, w00, fmaf(xr.y, w01, fmaf(xr.z, w02, fmaf(xr.w, w03, a0[r]))));
                a1[r] = fmaf(xr.x, w10, fmaf(xr.y, w11, fmaf(xr.z, w12, fmaf(xr.w, w13, a1[r]))));
            }
        }
        const float bk0 = b1[k0], bk1 = b1[k1];
#pragma unroll
        for (int r = 0; r < 10; ++r) {
            s_mid[r][k0] = gelu_exact(a0[r] + bk0);
            s_mid[r][k1] = gelu_exact(a1[r] + bk1);
        }
    }
    __syncthreads();

    // mlp2: thread owns col c, its 5 rows
    float out0 = 0.f, out1 = 0.f, out2 = 0.f, out3 = 0.f, out4 = 0.f;
    for (int k4 = 0; k4 < 512; k4 += 4) {
        float wv0 = w2[(k4 + 0) * 128 + c], wv1 = w2[(k4 + 1) * 128 + c];
        float wv2 = w2[(k4 + 2) * 128 + c], wv3 = w2[(k4 + 3) * 128 + c];
#define M2ROW(OUT, J) { \
        float4 mv = ld4(&s_mid[pg2 + 2 * (J)][k4]); \
        OUT = fmaf(mv.x, wv0, fmaf(mv.y, wv1, fmaf(mv.z, wv2, fmaf(mv.w, wv3, OUT)))); }
        M2ROW(out0, 0) M2ROW(out1, 1) M2ROW(out2, 2) M2ROW(out3, 3) M2ROW(out4, 4)
#undef M2ROW
    }
    const float bb = b2[c];
    float* hp = h + (m * NORI + ph * 10 + pg2) * CDIM + c;
    hp[0 * 2 * CDIM] += out0 + bb;
    hp[1 * 2 * CDIM] += out1 + bb;
    hp[2 * 2 * CDIM] += out2 + bb;
    hp[3 * 2 * CDIM] += out3 + bb;
    hp[4 * 2 * CDIM] += out4 + bb;
}

// ---------------------------------------------------------------------------
extern "C" void kernel_launch(void* const* d_in, const int* in_sizes, int n_in,
                              void* d_out, int out_size, void* d_ws, size_t ws_size,
                              hipStream_t stream)
{
    const float* x        = (const float*)d_in[0];
    const float* pos      = (const float*)d_in[1];
    const float* bw1      = (const float*)d_in[2];
    const float* bb1      = (const float*)d_in[3];
    const float* bw2      = (const float*)d_in[4];
    const float* bb2      = (const float*)d_in[5];
    const float* fw1      = (const float*)d_in[6];
    const float* fb1      = (const float*)d_in[7];
    const float* fw2      = (const float*)d_in[8];
    const float* fb2      = (const float*)d_in[9];
    const float* emb_w    = (const float*)d_in[10];
    const float* kernel_w = (const float*)d_in[11];
    const float* fiber_w  = (const float*)d_in[12];
    const float* conv_b   = (const float*)d_in[13];
    const float* ln_g     = (const float*)d_in[14];
    const float* ln_b     = (const float*)d_in[15];
    const float* mlp_w1   = (const float*)d_in[16];
    const float* mlp_b1   = (const float*)d_in[17];
    const float* mlp_w2   = (const float*)d_in[18];
    const float* mlp_b2   = (const float*)d_in[19];

    float* h = (float*)d_out;                       // [160,20,128]

    // ws layout (total 1,941,504 B, inside the r5-proven [0, 2,048,000 B)):
    unsigned short* wt = (unsigned short*)d_ws;     // [3][128][128] f16 = 98,304 B
    unsigned short* fk = wt + 3 * CDIM * CDIM;      // [2,20,20,128] f16 = 204,800 B
    float* x1 = (float*)(fk + 2 * NORI * NORI * CDIM);  // [160,20,128] f32 = 1,638,400 B

    wt_kernel<<<3 * CDIM, 128, 0, stream>>>(bw2, kernel_w, wt);
    fk_kernel<<<2 * NORI * NORI, 128, 0, stream>>>(fw1, fb1, fw2, fb2, fiber_w, fk);
    h0_kernel<<<NPTS * NORI, 128, 0, stream>>>(x, emb_w, h);

    for (int l = 0; l < 2; ++l) {
        x1_kernel<<<NPTS * NORI, 512, 0, stream>>>(
            pos, h, bw1, bb1, bb2, wt, wt + (1 + l) * CDIM * CDIM, x1);
        mlp_kernel<<<NPTS * 2, 256, 0, stream>>>(
            x1, fk + l * NORI * NORI * CDIM,
            conv_b + l * CDIM, ln_g + l * CDIM, ln_b + l * CDIM,
            mlp_w1 + l * CDIM * 4 * CDIM, mlp_b1 + l * 4 * CDIM,
            mlp_w2 + l * 4 * CDIM * CDIM, mlp_b2 + l * CDIM, h);
    }
}